// Round 9
// baseline (361.440 us; speedup 1.0000x reference)
//
#include <hip/hip_runtime.h>
#include <hip/hip_bf16.h>

typedef __attribute__((ext_vector_type(8))) short short8;
typedef __attribute__((ext_vector_type(4))) float f32x4;

#define LSTR 268  // f32 row stride for A/C: 1072B rows -> 16B-aligned, <=2-way banks

__device__ __forceinline__ unsigned short f2bf_rne(float x) {
  unsigned u = __float_as_uint(x);
  return (unsigned short)((u + 0x7FFFu + ((u >> 16) & 1u)) >> 16);
}

// scalar cast the compiler fuses into v_cvt_pk_bf16_f32 pairs (m240)
__device__ __forceinline__ short bfc(float x) {
  __hip_bfloat16 h = __float2bfloat16(x);
  return __builtin_bit_cast(short, h);
}

// ---- prep: weights -> bf16, fragment-transposed into d_ws (once per launch) ----
__global__ __launch_bounds__(256) void prep_kernel(
    const float* __restrict__ gW0, const float* __restrict__ gW1,
    unsigned short* __restrict__ W0T, unsigned short* __restrict__ W1T)
{
  const int t = blockIdx.x * 256 + threadIdx.x;  // 0..65535
  {
    const int c = t >> 7, k = t & 127;
    const int src = (k + ((c >= 256) ? 128 : 0)) * 256 + (c & 255);
    W0T[t] = f2bf_rne(gW0[src]);
  }
  {
    const int n = t >> 8, k = t & 255;
    W1T[t] = f2bf_rne(gW1[k * 256 + n]);
  }
}

// ---- main: per-(batch, i-half) pair MLP + partial pooled sum ----
// Round 2-8 evidence: per-kk step runs at ~770 cyc vs ~120 cyc of issue ->
// latency-bound; time scaled 121->82.5 us going 1->2 waves/SIMD. This round
// buys 4-way wave interleaving: grid 2048, block (2b+h) handles i in
// [8h, 8h+8) only. Phase 2 (32 MFMA/wave) is duplicated -- cheap. VGPR/LDS
// unchanged -> 4 blocks/CU resident. launch_bounds(256,4) matches the
// ~120-reg codegen the compiler insists on (r3-r8: remat/spill otherwise).
__global__ __launch_bounds__(256, 4) void pair_kernel(
    const float* __restrict__ state,
    const unsigned short* __restrict__ W0T, const float* __restrict__ gb0,
    const unsigned short* __restrict__ W1T, const float* __restrict__ gb1,
    float* __restrict__ parts)   // [B][2][256]
{
  const int b    = blockIdx.x >> 1;
  const int half = blockIdx.x & 1;
  const int tid  = threadIdx.x;
  const int w    = tid >> 6;   // wave 0..3
  const int l    = tid & 63;
  const int lr   = l & 15;
  const int lg   = l >> 4;

  __shared__ float A_lds[16 * LSTR];
  __shared__ float C_lds[16 * LSTR];

  const float* stb = state + (size_t)b * 2048;

  // ---------------- Phase 2: [A|C] = state[16x128] @ W0 ----------------
  short8 sfrag[4];
  #pragma unroll
  for (int kk = 0; kk < 4; ++kk) {
    const float* sp = stb + lr * 128 + kk * 32 + lg * 8;
    f32x4 s0 = *(const f32x4*)sp;
    f32x4 s1 = *(const f32x4*)(sp + 4);
    short8 f;
    f[0] = bfc(s0[0]); f[1] = bfc(s0[1]); f[2] = bfc(s0[2]); f[3] = bfc(s0[3]);
    f[4] = bfc(s1[0]); f[5] = bfc(s1[1]); f[6] = bfc(s1[2]); f[7] = bfc(s1[3]);
    sfrag[kk] = f;
  }

  const f32x4 z4 = {0.f, 0.f, 0.f, 0.f};
  f32x4 acc2[8];
  #pragma unroll
  for (int nt = 0; nt < 8; ++nt) acc2[nt] = z4;

  #pragma unroll
  for (int nt = 0; nt < 8; ++nt) {
    const int col = 128 * w + 16 * nt + lr;       // [A|C] col in [0,512)
    #pragma unroll
    for (int kk = 0; kk < 4; ++kk) {
      short8 bf = *(const short8*)(W0T + (size_t)col * 128 + kk * 32 + lg * 8);
      acc2[nt] = __builtin_amdgcn_mfma_f32_16x16x32_bf16(sfrag[kk], bf, acc2[nt], 0, 0, 0);
    }
  }

  // gW1 fragments (wave w owns N-cols [64w,64w+64))
  short8 bw[4][8];
  #pragma unroll
  for (int nt = 0; nt < 4; ++nt) {
    const int n = 64 * w + 16 * nt + lr;
    #pragma unroll
    for (int kk = 0; kk < 8; ++kk)
      bw[nt][kk] = *(const short8*)(W1T + (size_t)n * 256 + kk * 32 + lg * 8);
  }
  float gb1v[4];
  #pragma unroll
  for (int nt = 0; nt < 4; ++nt) gb1v[nt] = gb1[64 * w + 16 * nt + lr];

  // store phase-2 results (C/D layout: col=lr, row=lg*4+r)
  #pragma unroll
  for (int nt = 0; nt < 8; ++nt) {
    const int col = 128 * w + 16 * nt + lr;
    #pragma unroll
    for (int r = 0; r < 4; ++r) {
      const int row = lg * 4 + r;
      float v = acc2[nt][r];
      if (col < 256) A_lds[row * LSTR + col]       = v + gb0[col];  // fold gb0
      else           C_lds[row * LSTR + col - 256] = v;
    }
  }
  __syncthreads();

  // C rows -> registers: lane (lr,lg) holds C[lr][kk*32+lg*8 .. +8], kk=0..7
  f32x4 creg[16];
  #pragma unroll
  for (int kk = 0; kk < 8; ++kk) {
    const float* cp = &C_lds[lr * LSTR + kk * 32 + lg * 8];
    creg[2 * kk]     = *(const f32x4*)cp;
    creg[2 * kk + 1] = *(const f32x4*)(cp + 4);
  }

  // ---------------- Phase 3: 8 i-tiles (this block's half) ----------------
  float pp[4] = {0.f, 0.f, 0.f, 0.f};
  #pragma unroll 1
  for (int ii = 0; ii < 8; ++ii) {
    const int i = half * 8 + ii;
    f32x4 acc[4];
    #pragma unroll
    for (int nt = 0; nt < 4; ++nt) acc[nt] = z4;

    #pragma unroll
    for (int kk = 0; kk < 8; ++kk) {
      const float* ap = &A_lds[i * LSTR + kk * 32 + lg * 8];  // wave-uniform bcast
      f32x4 a0 = *(const f32x4*)ap;
      f32x4 a1 = *(const f32x4*)(ap + 4);
      f32x4 s0 = __builtin_elementwise_max(a0 + creg[2 * kk],     z4);
      f32x4 s1 = __builtin_elementwise_max(a1 + creg[2 * kk + 1], z4);
      short8 u;
      u[0] = bfc(s0[0]); u[1] = bfc(s0[1]); u[2] = bfc(s0[2]); u[3] = bfc(s0[3]);
      u[4] = bfc(s1[0]); u[5] = bfc(s1[1]); u[6] = bfc(s1[2]); u[7] = bfc(s1[3]);
      #pragma unroll
      for (int nt = 0; nt < 4; ++nt)
        acc[nt] = __builtin_amdgcn_mfma_f32_16x16x32_bf16(u, bw[nt][kk], acc[nt], 0, 0, 0);
    }

    #pragma unroll
    for (int nt = 0; nt < 4; ++nt) {
      #pragma unroll
      for (int r4 = 0; r4 < 4; ++r4) {
        const int row = lg * 4 + r4;       // = j
        const float v = fmaxf(acc[nt][r4] + gb1v[nt], 0.f);
        pp[nt] += (row == i) ? 0.f : v;    // mask the (i,i) filler pair
      }
    }
  }

  // reduce the 4 lane-groups; write this half's partial pooled
  #pragma unroll
  for (int nt = 0; nt < 4; ++nt) {
    float v = pp[nt];
    v += __shfl_xor(v, 16);
    v += __shfl_xor(v, 32);
    if (lg == 0)
      parts[((size_t)b * 2 + half) * 256 + 64 * w + 16 * nt + lr] = v;
  }
}

// ---- f-MLP: 8 batches per block; sums the two pooled halves on load ----
__global__ __launch_bounds__(256) void fmlp_kernel(
    const float* __restrict__ parts,
    const float* __restrict__ fW0, const float* __restrict__ fb0,
    const float* __restrict__ fW1, const float* __restrict__ fb1,
    float* __restrict__ out)
{
  const int tid = threadIdx.x;
  const size_t b0 = (size_t)blockIdx.x * 8;
  __shared__ float pl[8][256];
  __shared__ float h1[8][256];

  #pragma unroll
  for (int q = 0; q < 8; ++q) {
    const int idx = q * 256 + tid;
    const int qb = idx >> 8, c = idx & 255;
    pl[qb][c] = parts[(b0 + qb) * 512 + c] + parts[(b0 + qb) * 512 + 256 + c];
  }
  __syncthreads();

  float acc[8] = {0.f, 0.f, 0.f, 0.f, 0.f, 0.f, 0.f, 0.f};
  #pragma unroll 4
  for (int k = 0; k < 256; ++k) {
    const float wv = fW0[(size_t)k * 256 + tid];
    #pragma unroll
    for (int q = 0; q < 8; ++q) acc[q] = fmaf(pl[q][k], wv, acc[q]);
  }
  #pragma unroll
  for (int q = 0; q < 8; ++q) h1[q][tid] = fmaxf(acc[q] + fb0[tid], 0.f);
  __syncthreads();

  float acc2[8] = {0.f, 0.f, 0.f, 0.f, 0.f, 0.f, 0.f, 0.f};
  #pragma unroll 4
  for (int k = 0; k < 256; ++k) {
    const float wv = fW1[(size_t)k * 256 + tid];
    #pragma unroll
    for (int q = 0; q < 8; ++q) acc2[q] = fmaf(h1[q][k], wv, acc2[q]);
  }
  #pragma unroll
  for (int q = 0; q < 8; ++q)
    out[(b0 + q) * 256 + tid] = fmaxf(acc2[q] + fb1[tid], 0.f);
}

extern "C" void kernel_launch(void* const* d_in, const int* in_sizes, int n_in,
                              void* d_out, int out_size, void* d_ws, size_t ws_size,
                              hipStream_t stream) {
  const float* state = (const float*)d_in[0];
  const float* gW0   = (const float*)d_in[1];
  const float* gb0   = (const float*)d_in[2];
  const float* gW1   = (const float*)d_in[3];
  const float* gb1   = (const float*)d_in[4];
  const float* fW0   = (const float*)d_in[5];
  const float* fb0   = (const float*)d_in[6];
  const float* fW1   = (const float*)d_in[7];
  const float* fb1   = (const float*)d_in[8];
  float* out = (float*)d_out;

  unsigned short* W0T = (unsigned short*)d_ws;          // 512*128 bf16 = 128KB
  unsigned short* W1T = W0T + 512 * 128;                // 256*256 bf16 = 128KB
  float* parts = (float*)(W1T + 256 * 256);             // 1024*2*256 f32 = 2MB

  const int Bn = in_sizes[0] / 2048;  // 1024

  prep_kernel<<<dim3(256), dim3(256), 0, stream>>>(gW0, gW1, W0T, W1T);
  pair_kernel<<<dim3(2 * Bn), dim3(256), 0, stream>>>(state, W0T, gb0, W1T, gb1, parts);
  fmlp_kernel<<<dim3(Bn / 8), dim3(256), 0, stream>>>(parts, fW0, fb0, fW1, fb1, out);
}

// Round 10
// 75.491 us; speedup vs baseline: 4.7879x; 4.7879x over previous
//
#include <hip/hip_runtime.h>

typedef __attribute__((ext_vector_type(8))) _Float16 f16x8;
typedef __attribute__((ext_vector_type(4))) float f32x4;

#define HSTR 264   // halves per A/C row (528B = 33*16B: 16B-aligned, 4-bank row shift)

// ---- prep: weights -> fp16, fragment-contiguous (lane-major) into d_ws ----
// Layout puts one wave-fragment (64 lanes x 16B) contiguous -> every in-kernel
// weight load is a single fully-coalesced 1KB dwordx4 transaction.
// W0c elem: ((k>>5)*32 + (c>>4))*512 + (((k>>3)&3)*16 + (c&15))*8 + (k&7)
// W1c elem: ((k>>5)*16 + (n>>4))*512 + (((k>>3)&3)*16 + (n&15))*8 + (k&7)
__global__ __launch_bounds__(256) void prep_kernel(
    const float* __restrict__ gW0, const float* __restrict__ gW1,
    _Float16* __restrict__ W0c, _Float16* __restrict__ W1c)
{
  const int t = blockIdx.x * 256 + threadIdx.x;  // 0..65535
  {
    const int c = t >> 7, k = t & 127;           // c in [0,512), k in [0,128)
    const int dst = ((k >> 5) * 32 + (c >> 4)) * 512 +
                    (((k >> 3) & 3) * 16 + (c & 15)) * 8 + (k & 7);
    const int src = (k + ((c >= 256) ? 128 : 0)) * 256 + (c & 255);
    W0c[dst] = (_Float16)gW0[src];
  }
  {
    const int n = t >> 8, k = t & 255;           // n in [0,256), k in [0,256)
    const int dst = ((k >> 5) * 16 + (n >> 4)) * 512 +
                    (((k >> 3) & 3) * 16 + (n & 15)) * 8 + (k & 7);
    W1c[dst] = (_Float16)gW1[k * 256 + n];
  }
}

// ---- main: per-batch pair MLP + pooled sum, fp16, 8 waves ----
// Rounds 2-9 diagnosis: weight fragments were remat'd from L2 AT USE (~2GB
// L2 reads/dispatch ~ 24TB/s, never pipelined) because 4-wave/64-col slices
// need 128 VGPR of weights -- over the allocator's 128-reg target. This
// version: 8 waves x 32 cols -> bw = 64 VGPR, fp16 creg = 32, acc = 8;
// total ~120 <= 128 (launch_bounds(512,4)) -> nothing remats, weights load
// ONCE per wave (16 coalesced 1KB loads). u-build: pk_add_f16 + pk_max_f16
// straight into the f16 MFMA fragment (no cvt chain).
__global__ __launch_bounds__(512, 4) void pair_kernel(
    const float* __restrict__ state,
    const _Float16* __restrict__ W0c, const float* __restrict__ gb0,
    const _Float16* __restrict__ W1c, const float* __restrict__ gb1,
    float* __restrict__ pooled)
{
  const int b   = blockIdx.x;
  const int tid = threadIdx.x;
  const int w   = tid >> 6;   // wave 0..7
  const int l   = tid & 63;
  const int lr  = l & 15;
  const int lg  = l >> 4;

  __shared__ _Float16 A_lds[16 * HSTR];
  __shared__ _Float16 C_lds[16 * HSTR];

  const float* stb = state + (size_t)b * 2048;

  // ---------------- Phase 2: [A|C] = state[16x128] @ W0 (fp16 MFMA) ----------------
  f16x8 sfrag[4];
  #pragma unroll
  for (int kk = 0; kk < 4; ++kk) {
    const float* sp = stb + lr * 128 + kk * 32 + lg * 8;
    f32x4 s0 = *(const f32x4*)sp;
    f32x4 s1 = *(const f32x4*)(sp + 4);
    f16x8 f;
    f[0] = (_Float16)s0[0]; f[1] = (_Float16)s0[1];
    f[2] = (_Float16)s0[2]; f[3] = (_Float16)s0[3];
    f[4] = (_Float16)s1[0]; f[5] = (_Float16)s1[1];
    f[6] = (_Float16)s1[2]; f[7] = (_Float16)s1[3];
    sfrag[kk] = f;
  }

  const f32x4 z4 = {0.f, 0.f, 0.f, 0.f};
  f32x4 acc2[4];
  #pragma unroll
  for (int nt = 0; nt < 4; ++nt) acc2[nt] = z4;

  // wave w owns [A|C] cols [64w, 64w+64)
  #pragma unroll
  for (int nt = 0; nt < 4; ++nt) {
    #pragma unroll
    for (int kk = 0; kk < 4; ++kk) {
      f16x8 bf = *(const f16x8*)(W0c + (size_t)((kk * 32 + 4 * w + nt) * 512 + l * 8));
      acc2[nt] = __builtin_amdgcn_mfma_f32_16x16x32_f16(sfrag[kk], bf, acc2[nt], 0, 0, 0);
    }
  }

  // store phase-2 results as fp16 (C/D layout: col=lr, row=lg*4+r); fold gb0
  #pragma unroll
  for (int nt = 0; nt < 4; ++nt) {
    const int col = 64 * w + 16 * nt + lr;
    #pragma unroll
    for (int r = 0; r < 4; ++r) {
      const int row = lg * 4 + r;
      const float v = acc2[nt][r];
      if (col < 256) A_lds[row * HSTR + col]       = (_Float16)(v + gb0[col]);
      else           C_lds[row * HSTR + col - 256] = (_Float16)v;
    }
  }
  __syncthreads();

  // C rows -> fp16 registers: lane (lr,lg) holds C[lr][kk*32+lg*8 .. +8]
  f16x8 creg[8];
  #pragma unroll
  for (int kk = 0; kk < 8; ++kk)
    creg[kk] = *(const f16x8*)&C_lds[lr * HSTR + kk * 32 + lg * 8];

  // W1 fragments: wave w owns N-cols [32w, 32w+32) -> 2nt x 8kk = 64 VGPR, resident
  f16x8 bw[2][8];
  #pragma unroll
  for (int nt = 0; nt < 2; ++nt)
    #pragma unroll
    for (int kk = 0; kk < 8; ++kk)
      bw[nt][kk] = *(const f16x8*)(W1c + (size_t)((kk * 16 + 2 * w + nt) * 512 + l * 8));

  float gb1v[2];
  #pragma unroll
  for (int nt = 0; nt < 2; ++nt) gb1v[nt] = gb1[32 * w + 16 * nt + lr];

  const f16x8 zh = {(_Float16)0, (_Float16)0, (_Float16)0, (_Float16)0,
                    (_Float16)0, (_Float16)0, (_Float16)0, (_Float16)0};

  // ---------------- Phase 3: 16 i-tiles; u = relu(A_i + C_j) in fp16 ----------------
  float pp[2] = {0.f, 0.f};
  #pragma unroll 1
  for (int i = 0; i < 16; ++i) {
    f32x4 acc0 = z4, acc1 = z4;
    #pragma unroll
    for (int kk = 0; kk < 8; ++kk) {
      f16x8 a = *(const f16x8*)&A_lds[i * HSTR + kk * 32 + lg * 8];  // wave-uniform bcast
      f16x8 u = __builtin_elementwise_max(a + creg[kk], zh);
      acc0 = __builtin_amdgcn_mfma_f32_16x16x32_f16(u, bw[0][kk], acc0, 0, 0, 0);
      acc1 = __builtin_amdgcn_mfma_f32_16x16x32_f16(u, bw[1][kk], acc1, 0, 0, 0);
    }
    #pragma unroll
    for (int r = 0; r < 4; ++r) {
      const int row = lg * 4 + r;       // = j
      const float v0 = fmaxf(acc0[r] + gb1v[0], 0.f);
      const float v1 = fmaxf(acc1[r] + gb1v[1], 0.f);
      pp[0] += (row == i) ? 0.f : v0;   // mask the (i,i) filler pair
      pp[1] += (row == i) ? 0.f : v1;
    }
  }

  // reduce the 4 lane-groups (disjoint j subsets, same col), write pooled
  #pragma unroll
  for (int nt = 0; nt < 2; ++nt) {
    float v = pp[nt];
    v += __shfl_xor(v, 16);
    v += __shfl_xor(v, 32);
    if (lg == 0) pooled[(size_t)b * 256 + 32 * w + 16 * nt + lr] = v;
  }
}

// ---- f-MLP: 8 batches per block -> 8x weight reuse per load (fp32) ----
__global__ __launch_bounds__(256) void fmlp_kernel(
    const float* __restrict__ pooled,
    const float* __restrict__ fW0, const float* __restrict__ fb0,
    const float* __restrict__ fW1, const float* __restrict__ fb1,
    float* __restrict__ out)
{
  const int tid = threadIdx.x;
  const size_t b0 = (size_t)blockIdx.x * 8;
  __shared__ float pl[8][256];
  __shared__ float h1[8][256];

  #pragma unroll
  for (int q = 0; q < 8; ++q) {
    const int idx = q * 256 + tid;
    pl[idx >> 8][idx & 255] = pooled[b0 * 256 + idx];
  }
  __syncthreads();

  float acc[8] = {0.f, 0.f, 0.f, 0.f, 0.f, 0.f, 0.f, 0.f};
  #pragma unroll 4
  for (int k = 0; k < 256; ++k) {
    const float wv = fW0[(size_t)k * 256 + tid];
    #pragma unroll
    for (int q = 0; q < 8; ++q) acc[q] = fmaf(pl[q][k], wv, acc[q]);
  }
  #pragma unroll
  for (int q = 0; q < 8; ++q) h1[q][tid] = fmaxf(acc[q] + fb0[tid], 0.f);
  __syncthreads();

  float acc2[8] = {0.f, 0.f, 0.f, 0.f, 0.f, 0.f, 0.f, 0.f};
  #pragma unroll 4
  for (int k = 0; k < 256; ++k) {
    const float wv = fW1[(size_t)k * 256 + tid];
    #pragma unroll
    for (int q = 0; q < 8; ++q) acc2[q] = fmaf(h1[q][k], wv, acc2[q]);
  }
  #pragma unroll
  for (int q = 0; q < 8; ++q)
    out[(b0 + q) * 256 + tid] = fmaxf(acc2[q] + fb1[tid], 0.f);
}

extern "C" void kernel_launch(void* const* d_in, const int* in_sizes, int n_in,
                              void* d_out, int out_size, void* d_ws, size_t ws_size,
                              hipStream_t stream) {
  const float* state = (const float*)d_in[0];
  const float* gW0   = (const float*)d_in[1];
  const float* gb0   = (const float*)d_in[2];
  const float* gW1   = (const float*)d_in[3];
  const float* gb1   = (const float*)d_in[4];
  const float* fW0   = (const float*)d_in[5];
  const float* fb0   = (const float*)d_in[6];
  const float* fW1   = (const float*)d_in[7];
  const float* fb1   = (const float*)d_in[8];
  float* out = (float*)d_out;

  _Float16* W0c = (_Float16*)d_ws;                      // 65536 fp16 = 128KB
  _Float16* W1c = W0c + 65536;                          // 65536 fp16 = 128KB
  float* pooled = (float*)(W1c + 65536);                // 1024*256 f32 = 1MB

  const int Bn = in_sizes[0] / 2048;  // 1024

  prep_kernel<<<dim3(256), dim3(256), 0, stream>>>(gW0, gW1, W0c, W1c);
  pair_kernel<<<dim3(Bn), dim3(512), 0, stream>>>(state, W0c, gb0, W1c, gb1, pooled);
  fmlp_kernel<<<dim3(Bn / 8), dim3(256), 0, stream>>>(pooled, fW0, fb0, fW1, fb1, out);
}